// Round 10
// baseline (10456.734 us; speedup 1.0000x reference)
//
#include <hip/hip_runtime.h>
#include <math.h>

#define BB 128
#define TT 256
#define TMEL 800
#define EE 512
#define HH 1024
#define MELD 128
#define VV 256

// ws offsets (float units)
#define OFF_PROJ  0u
#define OFF_T1    131072u
#define OFF_WR2   524288u
#define OFF_BB1   1310720u
#define OFF_BB2   1311232u
#define OFF_B2    1311744u
#define OFF_W2C   1315840u
#define OFF_WENCR 5522688u
#define OFF_WIHS  7619840u
#define OFF_W2CR  8668416u
#define OFF_WHHDS 10765568u
#define OFF_WPGS  12862720u
#define OFF_H2B   12936448u
#define OFF_RING  21325056u   /* aliases h1pb (dead after conv2); 104 slots x 256KB */

typedef __bf16 bfv8 __attribute__((ext_vector_type(8)));
typedef float f32x4 __attribute__((ext_vector_type(4)));

__device__ __forceinline__ unsigned short f2b(float f){
  union { float f; unsigned u; } v; v.f = f;
  unsigned u = v.u;
  return (unsigned short)((u + 0x7fffu + ((u>>16)&1u)) >> 16);
}
__device__ __forceinline__ float sigm(float x){ return 1.0f/(1.0f+expf(-x)); }

__device__ __forceinline__ f32x4 mfma16(bfv8 a, bfv8 b, f32x4 c){
  return __builtin_amdgcn_mfma_f32_16x16x32_bf16(a, b, c, 0, 0, 0);
}

// ---- fp32 precompute kernels ----

__global__ void k_proj(const float* __restrict__ emb, const float* __restrict__ W,
                       const float* __restrict__ bias, float* __restrict__ proj){
  __shared__ float er[EE];
  int v = blockIdx.x;
  for(int i=threadIdx.x;i<EE;i+=256) er[i]=emb[v*EE+i];
  __syncthreads();
  for(int e=threadIdx.x;e<EE;e+=256){
    const float* wr = W + e*EE;
    float acc=0.f;
    for(int k=0;k<EE;k+=4){
      float4 w4 = *(const float4*)(wr+k);
      acc += er[k]*w4.x + er[k+1]*w4.y + er[k+2]*w4.z + er[k+3]*w4.w;
    }
    proj[v*EE+e] = acc + bias[e];
  }
}

__global__ void k_t1(const float* __restrict__ proj, const float* __restrict__ W1,
                     const float* __restrict__ g1, float* __restrict__ T1){
  __shared__ float pr[EE];
  int v = blockIdx.x; int k3 = blockIdx.y;
  for(int i=threadIdx.x;i<EE;i+=256) pr[i]=proj[v*EE+i];
  __syncthreads();
  const float s = rsqrtf(1.f+1e-5f);
  for(int c=threadIdx.x;c<EE;c+=256){
    float acc=0.f;
    const float* w = W1 + c*EE*3 + k3;
    for(int ci=0;ci<EE;ci++) acc += pr[ci]*w[ci*3];
    T1[(v*3+k3)*EE+c] = g1[c]*s*acc;
  }
}

__global__ void k_wr2(const float* __restrict__ W2, const float* __restrict__ g2,
                      unsigned short* __restrict__ Wr){
  int idx = blockIdx.x*256+threadIdx.x;
  if(idx >= EE*3*EE) return;
  int c = idx/1536; int r = idx%1536; int k3 = r/EE; int ci = r%EE;
  const float s = rsqrtf(1.f+1e-5f);
  Wr[idx] = f2b(g2[c]*s*W2[(c*EE+ci)*3+k3]);
}

__global__ void k_bb(const float* __restrict__ b1,const float* __restrict__ g1,const float* __restrict__ be1,
                     const float* __restrict__ b2,const float* __restrict__ g2,const float* __restrict__ be2,
                     float* __restrict__ bb1, float* __restrict__ bb2){
  int c = threadIdx.x + blockIdx.x*256; if(c>=EE) return;
  const float s = rsqrtf(1.f+1e-5f);
  bb1[c] = g1[c]*s*b1[c] + be1[c];
  bb2[c] = g2[c]*s*b2[c] + be2[c];
}

__global__ void k_b2(const float* __restrict__ bd, const float* __restrict__ Wih,
                     const float* __restrict__ bp, float* __restrict__ b2){
  int j = blockIdx.x*256+threadIdx.x; if(j>=4096) return;
  float acc = bd[j];
  const float* w = Wih + j*MELD;
  for(int m=0;m<MELD;m++) acc += w[m]*bp[m];
  b2[j] = acc;
}

__global__ void k_w2c(const float* __restrict__ Whh, const float* __restrict__ Wih,
                      const float* __restrict__ Wp, float* __restrict__ W2c){
  __shared__ float wl[8][MELD];
  int j0 = blockIdx.x*8; int k = blockIdx.y*256 + threadIdx.x;
  for(int i=threadIdx.x;i<8*MELD;i+=256) wl[i/MELD][i%MELD] = Wih[(j0+i/MELD)*MELD + (i%MELD)];
  __syncthreads();
  float acc[8];
  #pragma unroll
  for(int jj=0;jj<8;jj++) acc[jj]=Whh[(j0+jj)*HH+k];
  for(int m=0;m<MELD;m++){
    float wp = Wp[m*HH+k];
    #pragma unroll
    for(int jj=0;jj<8;jj++) acc[jj] += wl[jj][m]*wp;
  }
  #pragma unroll
  for(int jj=0;jj<8;jj++) W2c[(j0+jj)*HH+k] = acc[jj];
}

// ---- fragment packing ----
__global__ void k_pack(const float* __restrict__ src, unsigned short* __restrict__ dst,
                       int NKT, int K){
  int tile = blockIdx.x;
  int cg = tile>>3, wv = tile&7;
  int tot = NKT*64*8;
  for(int i=threadIdx.x; i<tot; i+=256){
    int kt = i>>9; int l = (i>>3)&63; int e = i&7;
    int j = (wv>>1)*1024 + cg*32 + (wv&1)*16 + (l&15);
    int k = ((l>>4)<<3) + kt*32 + e;
    dst[((size_t)(tile*NKT + kt)*64 + l)*8 + e] = f2b(src[(size_t)j*K + k]);
  }
}

__global__ void k_pack_pg(const float* __restrict__ Wp, const float* __restrict__ Wg,
                          unsigned short* __restrict__ dst){
  int nt = blockIdx.x; // 0..8
  for(int i=threadIdx.x; i<32*64*8; i+=256){
    int kt = i>>9; int l = (i>>3)&63; int e = i&7;
    int n = nt*16 + (l&15);
    int k = ((l>>4)<<3) + kt*32 + e;
    float v = (n<MELD)? Wp[(size_t)n*HH+k] : (n==MELD? Wg[k] : 0.f);
    dst[((size_t)(nt*32 + kt)*64 + l)*8 + e] = f2b(v);
  }
}

// ---- conv path ----

__global__ void k_pad(unsigned short* __restrict__ h1pb){
  int idx = blockIdx.x*256+threadIdx.x;
  int c = idx & 511; int b = idx >> 9;
  h1pb[((size_t)b*258)*EE + c] = 0;
  h1pb[((size_t)b*258 + 257)*EE + c] = 0;
}

__global__ void k_conv1(const int* __restrict__ x, const float* __restrict__ T1,
                        const float* __restrict__ bb1, unsigned short* __restrict__ h1pb){
  int idx = blockIdx.x*256+threadIdx.x;
  int c = idx & 511; int bt = idx >> 9; int t = bt & 255; int b = bt >> 8;
  float acc = bb1[c];
  if(t > 0)    acc += T1[(size_t)(x[b*TT+t-1]*3+0)*EE+c];
               acc += T1[(size_t)(x[b*TT+t  ]*3+1)*EE+c];
  if(t < TT-1) acc += T1[(size_t)(x[b*TT+t+1]*3+2)*EE+c];
  h1pb[((size_t)b*258 + t + 1)*EE + c] = f2b(fmaxf(acc, 0.f));
}

template<int NKT>
__device__ __forceinline__ void mm_seg_stream(const unsigned short* A, int lda,
    const unsigned short* Wrow, f32x4& acc0, f32x4& acc1, int l, int wv){
  int r0 = wv*32 + (l&15);
  int k8 = (l>>4)*8;
  const unsigned short* a0 = A + (size_t)r0*lda + k8;
  const unsigned short* a1 = a0 + 16*lda;
  const unsigned short* wp = Wrow + k8;
  #pragma unroll
  for(int kt=0;kt<NKT;kt++){
    bfv8 bv = *(const bfv8*)(const void*)(wp + kt*32);
    acc0 = mfma16(*(const bfv8*)(const void*)(a0 + kt*32), bv, acc0);
    acc1 = mfma16(*(const bfv8*)(const void*)(a1 + kt*32), bv, acc1);
  }
}

__global__ __launch_bounds__(256,2) void k_conv2mm(const unsigned short* __restrict__ h1pb,
    const unsigned short* __restrict__ Wr2b, const float* __restrict__ bb2,
    unsigned short* __restrict__ h2b){
  int b = blockIdx.x;    // 0..127
  int th = blockIdx.y;   // 0..1
  int nt = blockIdx.z;   // 0..31
  int tid=threadIdx.x; int wv=tid>>6, l=tid&63;
  const unsigned short* A = h1pb + ((size_t)b*258 + th*128)*EE;
  const unsigned short* Wrow = Wr2b + (size_t)(nt*16+(l&15))*1536;
  f32x4 acc0={0,0,0,0}, acc1={0,0,0,0};
  mm_seg_stream<48>(A, EE, Wrow, acc0, acc1, l, wv);
  int rr=(l>>4)*4, cc=l&15;
  int n = nt*16+cc;
  float bias = bb2[n];
  #pragma unroll
  for(int mi=0;mi<2;mi++){
    f32x4 acc = mi?acc1:acc0;
    int tb = th*128 + wv*32 + mi*16 + rr;
    #pragma unroll
    for(int q=0;q<4;q++){
      float v = fmaxf(acc[q]+bias, 0.f);
      h2b[((size_t)(tb+q)*BB + b)*EE + n] = f2b(v);
    }
  }
}

// ---- TAGGED-DATA SYNC (single-hop, barrier-free) ----
// Every h-dword (2 bf16 cols) carries the step epoch in its LSB (mangles one
// bf16 mantissa LSB, ~0.4% rel on half the elements -- absmax budget 20).
// Dword stores are single-copy atomic, so tag-valid => data-valid per dword:
// NO flags, NO arrive, NO fences. Consumer polls the data itself; producer
// fire-and-forgets. One coherence round-trip per step instead of three
// (rounds 4-9: store-ack + flag-store + poll-detect = ~5us of the 7.8us step).
// Slot reuse tags: enc 3-slot rotation, tag (k/3)&1; dec 101-slot ring (odd
// => parity flips on reuse), tag (t/101)&1. Max inter-WG skew is 1 step
// (each write is preceded by a full poll of the previous step), so a slot is
// never overwritten while readable -- incl. the chunk phase (reads [t-99..t],
// earliest overwrite is slot t+1 = t-100 mod 101).
__device__ __forceinline__ void stage_wait(unsigned short* hs, const unsigned short* slotp,
                                           int bg, int tid, unsigned int tagbit){
  const unsigned long long tagpat = (unsigned long long)tagbit * 0x0000000100000001ull;
  const unsigned long long* p[8];
  unsigned long long v[8];
  #pragma unroll
  for(int j=0;j<8;j++){
    int i = tid + j*512;
    int r = i >> 8, c8 = i & 255;
    p[j] = (const unsigned long long*)(slotp + (size_t)(bg*16+r)*HH + c8*4);
    v[j] = __hip_atomic_load(p[j], __ATOMIC_RELAXED, __HIP_MEMORY_SCOPE_AGENT);
  }
  #pragma unroll
  for(int j=0;j<8;j++){
    while(((v[j] ^ tagpat) & 0x0000000100000001ull) != 0ull){
      __builtin_amdgcn_s_sleep(1);
      v[j] = __hip_atomic_load(p[j], __ATOMIC_RELAXED, __HIP_MEMORY_SCOPE_AGENT);
    }
  }
  #pragma unroll
  for(int j=0;j<8;j++){
    int i = tid + j*512;
    int r = i >> 8, c8 = i & 255;
    *(unsigned long long*)((char*)hs + ((r*2048 + c8*8) ^ ((r&7)<<4))) = v[j];
  }
}

// ---- persistent recurrence: 256 WGs = 8 batch-groups x 32 col-groups. ----
__global__ __launch_bounds__(512,1) void k_recur(
  const unsigned short* __restrict__ h2b, unsigned short* __restrict__ ring,
  const unsigned short* __restrict__ WencR, const unsigned short* __restrict__ WihS,
  const unsigned short* __restrict__ W2cR, const unsigned short* __restrict__ WhhdS,
  const unsigned short* __restrict__ WpgS,
  const float* __restrict__ bhe, const float* __restrict__ bd, const float* __restrict__ b2,
  const float* __restrict__ bp, const float* __restrict__ bgp,
  const int* __restrict__ tlen, const int* __restrict__ mlen,
  float* __restrict__ outmel, float* __restrict__ outgate)
{
  __shared__ __align__(16) unsigned short hs[16*1024];  // 32KB
  __shared__ __align__(16) unsigned short Xs[16*512];   // 16KB
  __shared__ float Gs[16][132];

  const int bid = blockIdx.x;
  const int bg = bid >> 5, cg = bid & 31;
  const int tid = threadIdx.x;
  const int wvi = tid >> 6, l = tid & 63;
  const int tile = cg*8 + wvi;
  unsigned short* const encbase = ring + (size_t)101*BB*HH;

  const int fr = l & 15;
  const int hswz = (fr & 7) << 4;
  const int hbase = fr*2048 + ((l>>4)<<4);
  const int xbase = fr*1024 + ((l>>4)<<4);

  const int lr = tid >> 4;
  const int lc = (tid & 15) * 2;
  const int hcol = cg*32 + lc;
  float cs0 = 0.f, cs1 = 0.f;
  unsigned int hp = 0u;   // held (untagged) h pack for masked encoder rows
  int mylen = 0;
  if(tid < 256) mylen = tlen[bg*16 + lr];

  f32x4 bw[32];

  // ================= encoder: 256 steps =================
  {
    const f32x4* wsrc = (const f32x4*)(const void*)(WencR + ((size_t)(tile*32)*64 + l)*8);
    #pragma unroll
    for(int kt=0;kt<32;kt++) bw[kt] = wsrc[kt*64];
    #pragma unroll
    for(int kt=0;kt<32;kt++) asm volatile("" : "+v"(bw[kt]));
  }

  float ei0=0,ei1=0,ef0=0,ef1=0,eg0=0,eg1=0,eo0=0,eo1=0;
  if(tid < 256){
    ei0=bhe[hcol];      ei1=bhe[hcol+1];
    ef0=bhe[HH+hcol];   ef1=bhe[HH+hcol+1];
    eg0=bhe[2*HH+hcol]; eg1=bhe[2*HH+hcol+1];
    eo0=bhe[3*HH+hcol]; eo1=bhe[3*HH+hcol+1];
  }

  #pragma unroll 1
  for(int t=0;t<TT;t++){
    {
      const uint4* src = (const uint4*)(h2b + (size_t)(t*BB + bg*16)*EE);
      for(int i = tid; i < 1024; i += 512){
        int r = i >> 6, c16 = i & 63;
        uint4 v = src[r*64 + c16];
        *(uint4*)((char*)Xs + ((r*1024 + c16*16) ^ ((r&7)<<4))) = v;
      }
    }
    __syncthreads();
    f32x4 acc = {0.f,0.f,0.f,0.f};
    {
      const unsigned short* wsrc = WihS + (size_t)tile*16*64*8;
      #pragma unroll
      for(int kt=0;kt<16;kt++){
        bfv8 wf = *(const bfv8*)(const void*)(wsrc + ((size_t)kt*64 + l)*8);
        bfv8 xv = *(const bfv8*)(const void*)((const char*)Xs + ((xbase + kt*64) ^ hswz));
        acc = mfma16(xv, wf, acc);
      }
    }
    // h_t: slot t%3, tag (t/3)&1  (t=0: memset zeros, tag 0 => h_0 = 0, valid)
    stage_wait(hs, encbase + (size_t)(t%3)*BB*HH, bg, tid, (unsigned)((t/3)&1));
    __syncthreads();
    #pragma unroll
    for(int kt=0;kt<32;kt++){
      bfv8 hv = *(const bfv8*)(const void*)((const char*)hs + ((hbase + kt*64) ^ hswz));
      acc = mfma16(hv, __builtin_bit_cast(bfv8, bw[kt]), acc);
    }
    {
      int rr = (l>>4)*4;
      #pragma unroll
      for(int q=0;q<4;q++) Gs[rr+q][wvi*16 + fr] = acc[q];
    }
    __syncthreads();
    if(tid < 256){
      float gi0 = Gs[lr][lc]    + ei0, gi1 = Gs[lr][lc+1] + ei1;
      float gf0 = Gs[lr][32+lc] + ef0, gf1 = Gs[lr][33+lc] + ef1;
      float gg0 = Gs[lr][64+lc] + eg0, gg1 = Gs[lr][65+lc] + eg1;
      float go0 = Gs[lr][96+lc] + eo0, go1 = Gs[lr][97+lc] + eo1;
      float c20 = sigm(gf0)*cs0 + sigm(gi0)*tanhf(gg0);
      float c21 = sigm(gf1)*cs1 + sigm(gi1)*tanhf(gg1);
      float h20 = sigm(go0)*tanhf(c20);
      float h21 = sigm(go1)*tanhf(c21);
      if(t < mylen){
        cs0 = c20; cs1 = c21;
        hp = (unsigned)f2b(h20) | ((unsigned)f2b(h21)<<16);
      }
      // write h_{t+1}: slot (t+1)%3, tag ((t+1)/3)&1 (re-tag held rows too)
      unsigned int wtag = (unsigned)(((t+1)/3)&1);
      unsigned short* outslot = encbase + (size_t)((t+1)%3)*BB*HH;
      __hip_atomic_store((unsigned int*)(outslot + (size_t)(bg*16+lr)*HH + hcol),
                         (hp & ~1u) | wtag,
                         __ATOMIC_RELAXED, __HIP_MEMORY_SCOPE_AGENT);
    }
  }

  // ================= decoder: 800 steps =================
  {
    const f32x4* wsrc = (const f32x4*)(const void*)(W2cR + ((size_t)(tile*32)*64 + l)*8);
    #pragma unroll
    for(int kt=0;kt<32;kt++) bw[kt] = wsrc[kt*64];
    #pragma unroll
    for(int kt=0;kt<32;kt++) asm volatile("" : "+v"(bw[kt]));
  }

  float di0=0,di1=0,df0=0,df1=0,dg0=0,dg1=0,do0=0,do1=0;
  if(tid < 256){
    di0=b2[hcol];      di1=b2[hcol+1];
    df0=b2[HH+hcol];   df1=b2[HH+hcol+1];
    dg0=b2[2*HH+hcol]; dg1=b2[2*HH+hcol+1];
    do0=b2[3*HH+hcol]; do1=b2[3*HH+hcol+1];
  }

  #pragma unroll 1
  for(int t=0;t<TMEL;t++){
    // input h: t==0 -> encoder final h_256 (slot 256%3=1, tag (256/3)&1=1);
    // else decoder slot (t-1)%101, tag ((t-1)/101)&1
    const unsigned short* slotin;
    unsigned int ctag;
    if(t == 0){ slotin = encbase + (size_t)(TT%3)*BB*HH; ctag = (unsigned)((TT/3)&1); }
    else      { slotin = ring + (size_t)((t-1)%101)*BB*HH; ctag = (unsigned)(((t-1)/101)&1); }
    stage_wait(hs, slotin, bg, tid, ctag);
    __syncthreads();
    f32x4 acc = {0.f,0.f,0.f,0.f};
    if(t == 0){
      const unsigned short* wsrc = WhhdS + (size_t)tile*32*64*8;
      #pragma unroll
      for(int kt=0;kt<32;kt++){
        bfv8 wf = *(const bfv8*)(const void*)(wsrc + ((size_t)kt*64 + l)*8);
        bfv8 hv = *(const bfv8*)(const void*)((const char*)hs + ((hbase + kt*64) ^ hswz));
        acc = mfma16(hv, wf, acc);
      }
    } else {
      #pragma unroll
      for(int kt=0;kt<32;kt++){
        bfv8 hv = *(const bfv8*)(const void*)((const char*)hs + ((hbase + kt*64) ^ hswz));
        acc = mfma16(hv, __builtin_bit_cast(bfv8, bw[kt]), acc);
      }
    }
    {
      int rr = (l>>4)*4;
      #pragma unroll
      for(int q=0;q<4;q++) Gs[rr+q][wvi*16 + fr] = acc[q];
    }
    __syncthreads();
    if(tid < 256){
      float bi0=di0,bi1=di1,bf0=df0,bf1=df1,bg0=dg0,bg1=dg1,bo0=do0,bo1=do1;
      if(t==0){
        bi0=bd[hcol];      bi1=bd[hcol+1];
        bf0=bd[HH+hcol];   bf1=bd[HH+hcol+1];
        bg0=bd[2*HH+hcol]; bg1=bd[2*HH+hcol+1];
        bo0=bd[3*HH+hcol]; bo1=bd[3*HH+hcol+1];
      }
      float gi0 = Gs[lr][lc]    + bi0, gi1 = Gs[lr][lc+1] + bi1;
      float gf0 = Gs[lr][32+lc] + bf0, gf1 = Gs[lr][33+lc] + bf1;
      float gg0 = Gs[lr][64+lc] + bg0, gg1 = Gs[lr][65+lc] + bg1;
      float go0 = Gs[lr][96+lc] + bo0, go1 = Gs[lr][97+lc] + bo1;
      float c20 = sigm(gf0)*cs0 + sigm(gi0)*tanhf(gg0);
      float c21 = sigm(gf1)*cs1 + sigm(gi1)*tanhf(gg1);
      cs0 = c20; cs1 = c21;
      float h20 = sigm(go0)*tanhf(c20);
      float h21 = sigm(go1)*tanhf(c21);
      unsigned int pk = (unsigned)f2b(h20) | ((unsigned)f2b(h21)<<16);
      unsigned int wtag = (unsigned)((t/101)&1);
      unsigned short* outslot = ring + (size_t)(t%101)*BB*HH;
      __hip_atomic_store((unsigned int*)(outslot + (size_t)(bg*16+lr)*HH + hcol),
                         (pk & ~1u) | wtag,
                         __ATOMIC_RELAXED, __HIP_MEMORY_SCOPE_AGENT);
    }

    if((t%100)==99){
      int tbase = t - 99;
      #pragma unroll 1
      for(int s = cg; s < 100; s += 32){
        int u = tbase + s;
        stage_wait(hs, ring + (size_t)(u%101)*BB*HH, bg, tid, (unsigned)((u/101)&1));
        __syncthreads();
        #pragma unroll 1
        for(int pass=0; pass<2; pass++){
          int nt = (pass==0) ? wvi : 8;
          if(pass==1 && wvi!=0) break;
          const unsigned short* wsrc = WpgS + (size_t)nt*32*64*8;
          f32x4 acc2 = {0.f,0.f,0.f,0.f};
          #pragma unroll
          for(int kt=0;kt<32;kt++){
            bfv8 wf = *(const bfv8*)(const void*)(wsrc + ((size_t)kt*64 + l)*8);
            bfv8 hv = *(const bfv8*)(const void*)((const char*)hs + ((hbase + kt*64) ^ hswz));
            acc2 = mfma16(hv, wf, acc2);
          }
          int n = nt*16 + fr;
          #pragma unroll
          for(int q=0;q<4;q++){
            int b = bg*16 + (l>>4)*4 + q;
            bool msk = u > mlen[b];
            if(n < MELD)
              outmel[((size_t)b*TMEL + u)*MELD + n] = msk ? 0.f : acc2[q]+bp[n];
            else if(n == MELD)
              outgate[(size_t)b*TMEL + u] = msk ? 1000.f : acc2[q]+bgp[0];
          }
        }
        __syncthreads();
      }
    }
  }
}

__global__ void k_mask(const int* __restrict__ mlen, float* __restrict__ om){
  int idx=blockIdx.x*256+threadIdx.x; if(idx>=BB*TMEL) return;
  int b=idx/TMEL, t=idx%TMEL;
  om[idx] = (t > mlen[b]) ? 1.f : 0.f;
}

extern "C" void kernel_launch(void* const* d_in, const int* in_sizes, int n_in,
                              void* d_out, int out_size, void* d_ws, size_t ws_size,
                              hipStream_t stream){
  (void)in_sizes; (void)n_in; (void)out_size; (void)ws_size;
  const int*   x    = (const int*)d_in[0];
  const int*   tlen = (const int*)d_in[1];
  const int*   mlen = (const int*)d_in[3];
  const float* emb  = (const float*)d_in[4];
  const float* elW  = (const float*)d_in[5];
  const float* elb  = (const float*)d_in[6];
  const float* c1W  = (const float*)d_in[7];
  const float* c1b  = (const float*)d_in[8];
  const float* g1   = (const float*)d_in[9];
  const float* be1  = (const float*)d_in[10];
  const float* c2W  = (const float*)d_in[11];
  const float* c2b  = (const float*)d_in[12];
  const float* g2   = (const float*)d_in[13];
  const float* be2  = (const float*)d_in[14];
  const float* Wihe = (const float*)d_in[15];
  const float* Whhe = (const float*)d_in[16];
  const float* bhe  = (const float*)d_in[17];
  const float* Wihd = (const float*)d_in[18];
  const float* Whhd = (const float*)d_in[19];
  const float* bhd  = (const float*)d_in[20];
  const float* Wp   = (const float*)d_in[21];
  const float* bp   = (const float*)d_in[22];
  const float* Wg   = (const float*)d_in[23];
  const float* bg   = (const float*)d_in[24];

  float* ws = (float*)d_ws;
  float* proj = ws + OFF_PROJ;
  float* T1   = ws + OFF_T1;
  unsigned short* Wr2b = (unsigned short*)(ws + OFF_WR2);
  float* bb1 = ws + OFF_BB1;
  float* bb2 = ws + OFF_BB2;
  float* b2  = ws + OFF_B2;
  float* W2c = ws + OFF_W2C;
  unsigned short* WencR = (unsigned short*)(ws + OFF_WENCR);
  unsigned short* WihS  = (unsigned short*)(ws + OFF_WIHS);
  unsigned short* W2cR  = (unsigned short*)(ws + OFF_W2CR);
  unsigned short* WhhdS = (unsigned short*)(ws + OFF_WHHDS);
  unsigned short* WpgS  = (unsigned short*)(ws + OFF_WPGS);
  unsigned short* h2b   = (unsigned short*)(ws + OFF_H2B);
  unsigned short* h1pb  = (unsigned short*)(ws + OFF_RING); // conv scratch
  unsigned short* ring  = (unsigned short*)(ws + OFF_RING); // alias after conv2

  float* outmel  = (float*)d_out;
  float* outgate = outmel + (size_t)BB*TMEL*MELD;
  float* outmask = outgate + (size_t)BB*TMEL;

  k_proj<<<VV,256,0,stream>>>(emb, elW, elb, proj);
  k_t1<<<dim3(VV,3),256,0,stream>>>(proj, c1W, g1, T1);
  k_wr2<<<(EE*3*EE+255)/256,256,0,stream>>>(c2W, g2, Wr2b);
  k_bb<<<2,256,0,stream>>>(c1b,g1,be1,c2b,g2,be2,bb1,bb2);
  k_b2<<<16,256,0,stream>>>(bhd, Wihd, bp, b2);
  k_w2c<<<dim3(4096/8,HH/256),256,0,stream>>>(Whhd, Wihd, Wp, W2c);
  k_pack<<<256,256,0,stream>>>(Whhe, WencR, 32, 1024);
  k_pack<<<256,256,0,stream>>>(Wihe, WihS, 16, 512);
  k_pack<<<256,256,0,stream>>>(W2c,  W2cR, 32, 1024);
  k_pack<<<256,256,0,stream>>>(Whhd, WhhdS, 32, 1024);
  k_pack_pg<<<9,256,0,stream>>>(Wp, Wg, WpgS);
  k_pad<<<256,256,0,stream>>>(h1pb);
  k_conv1<<<65536,256,0,stream>>>(x, T1, bb1, h1pb);
  k_conv2mm<<<dim3(BB,2,32),256,0,stream>>>(h1pb, Wr2b, bb2, h2b);

  // ring tag-init AFTER conv (ring aliases h1pb). Runs every call (harness
  // does not re-poison between replays).
  // dec slots [0..101): init tag=1 (first write tag 0) -> 0x01 bytes
  hipMemsetAsync(ring, 0x01, (size_t)101*BB*HH*2, stream);
  // enc slot 0 = h_0: zeros with tag 0 -> 0x00
  hipMemsetAsync(ring + (size_t)101*BB*HH, 0x00, (size_t)BB*HH*2, stream);
  // enc slots 1,2: init tag=1 (first writes h_1,h_2 tag 0)
  hipMemsetAsync(ring + (size_t)102*BB*HH, 0x01, (size_t)2*BB*HH*2, stream);

  void* kargs[] = {
    (void*)&h2b, (void*)&ring, (void*)&WencR, (void*)&WihS, (void*)&W2cR, (void*)&WhhdS,
    (void*)&WpgS, (void*)&bhe, (void*)&bhd, (void*)&b2, (void*)&bp, (void*)&bg,
    (void*)&tlen, (void*)&mlen, (void*)&outmel, (void*)&outgate
  };
  hipLaunchCooperativeKernel((void*)k_recur, dim3(256), dim3(512), kargs, 0u, stream);

  k_mask<<<(BB*TMEL+255)/256,256,0,stream>>>(mlen, outmask);
}

// Round 12
// 7829.436 us; speedup vs baseline: 1.3356x; 1.3356x over previous
//
#include <hip/hip_runtime.h>
#include <math.h>

#define BB 128
#define TT 256
#define TMEL 800
#define EE 512
#define HH 1024
#define MELD 128
#define VV 256

// ws offsets (float units)
#define OFF_PROJ  0u
#define OFF_T1    131072u
#define OFF_WR2   524288u
#define OFF_BB1   1310720u
#define OFF_BB2   1311232u
#define OFF_B2    1311744u
#define OFF_W2C   1315840u
#define OFF_BAR   5510144u
#define OFF_WENCR 5522688u
#define OFF_WIHS  7619840u
#define OFF_W2CR  8668416u
#define OFF_WHHDS 10765568u
#define OFF_WPGS  12862720u
#define OFF_H2B   12936448u
#define OFF_RING  21325056u   /* aliases h1pb (dead after conv2) */

typedef __bf16 bfv8 __attribute__((ext_vector_type(8)));
typedef float f32x4 __attribute__((ext_vector_type(4)));
typedef unsigned u32x4 __attribute__((ext_vector_type(4)));

__device__ __forceinline__ unsigned short f2b(float f){
  union { float f; unsigned u; } v; v.f = f;
  unsigned u = v.u;
  return (unsigned short)((u + 0x7fffu + ((u>>16)&1u)) >> 16);
}
__device__ __forceinline__ float sigm(float x){ return 1.0f/(1.0f+expf(-x)); }

__device__ __forceinline__ f32x4 mfma16(bfv8 a, bfv8 b, f32x4 c){
  return __builtin_amdgcn_mfma_f32_16x16x32_bf16(a, b, c, 0, 0, 0);
}

// ---- fp32 precompute kernels ----

__global__ void k_proj(const float* __restrict__ emb, const float* __restrict__ W,
                       const float* __restrict__ bias, float* __restrict__ proj){
  __shared__ float er[EE];
  int v = blockIdx.x;
  for(int i=threadIdx.x;i<EE;i+=256) er[i]=emb[v*EE+i];
  __syncthreads();
  for(int e=threadIdx.x;e<EE;e+=256){
    const float* wr = W + e*EE;
    float acc=0.f;
    for(int k=0;k<EE;k+=4){
      float4 w4 = *(const float4*)(wr+k);
      acc += er[k]*w4.x + er[k+1]*w4.y + er[k+2]*w4.z + er[k+3]*w4.w;
    }
    proj[v*EE+e] = acc + bias[e];
  }
}

__global__ void k_t1(const float* __restrict__ proj, const float* __restrict__ W1,
                     const float* __restrict__ g1, float* __restrict__ T1){
  __shared__ float pr[EE];
  int v = blockIdx.x; int k3 = blockIdx.y;
  for(int i=threadIdx.x;i<EE;i+=256) pr[i]=proj[v*EE+i];
  __syncthreads();
  const float s = rsqrtf(1.f+1e-5f);
  for(int c=threadIdx.x;c<EE;c+=256){
    float acc=0.f;
    const float* w = W1 + c*EE*3 + k3;
    for(int ci=0;ci<EE;ci++) acc += pr[ci]*w[ci*3];
    T1[(v*3+k3)*EE+c] = g1[c]*s*acc;
  }
}

__global__ void k_wr2(const float* __restrict__ W2, const float* __restrict__ g2,
                      unsigned short* __restrict__ Wr){
  int idx = blockIdx.x*256+threadIdx.x;
  if(idx >= EE*3*EE) return;
  int c = idx/1536; int r = idx%1536; int k3 = r/EE; int ci = r%EE;
  const float s = rsqrtf(1.f+1e-5f);
  Wr[idx] = f2b(g2[c]*s*W2[(c*EE+ci)*3+k3]);
}

__global__ void k_bb(const float* __restrict__ b1,const float* __restrict__ g1,const float* __restrict__ be1,
                     const float* __restrict__ b2,const float* __restrict__ g2,const float* __restrict__ be2,
                     float* __restrict__ bb1, float* __restrict__ bb2){
  int c = threadIdx.x + blockIdx.x*256; if(c>=EE) return;
  const float s = rsqrtf(1.f+1e-5f);
  bb1[c] = g1[c]*s*b1[c] + be1[c];
  bb2[c] = g2[c]*s*b2[c] + be2[c];
}

__global__ void k_b2(const float* __restrict__ bd, const float* __restrict__ Wih,
                     const float* __restrict__ bp, float* __restrict__ b2){
  int j = blockIdx.x*256+threadIdx.x; if(j>=4096) return;
  float acc = bd[j];
  const float* w = Wih + j*MELD;
  for(int m=0;m<MELD;m++) acc += w[m]*bp[m];
  b2[j] = acc;
}

__global__ void k_w2c(const float* __restrict__ Whh, const float* __restrict__ Wih,
                      const float* __restrict__ Wp, float* __restrict__ W2c){
  __shared__ float wl[8][MELD];
  int j0 = blockIdx.x*8; int k = blockIdx.y*256 + threadIdx.x;
  for(int i=threadIdx.x;i<8*MELD;i+=256) wl[i/MELD][i%MELD] = Wih[(j0+i/MELD)*MELD + (i%MELD)];
  __syncthreads();
  float acc[8];
  #pragma unroll
  for(int jj=0;jj<8;jj++) acc[jj]=Whh[(j0+jj)*HH+k];
  for(int m=0;m<MELD;m++){
    float wp = Wp[m*HH+k];
    #pragma unroll
    for(int jj=0;jj<8;jj++) acc[jj] += wl[jj][m]*wp;
  }
  #pragma unroll
  for(int jj=0;jj<8;jj++) W2c[(j0+jj)*HH+k] = acc[jj];
}

// ---- fragment packing ----
__global__ void k_pack(const float* __restrict__ src, unsigned short* __restrict__ dst,
                       int NKT, int K){
  int tile = blockIdx.x;
  int cg = tile>>3, wv = tile&7;
  int tot = NKT*64*8;
  for(int i=threadIdx.x; i<tot; i+=256){
    int kt = i>>9; int l = (i>>3)&63; int e = i&7;
    int j = (wv>>1)*1024 + cg*32 + (wv&1)*16 + (l&15);
    int k = ((l>>4)<<3) + kt*32 + e;
    dst[((size_t)(tile*NKT + kt)*64 + l)*8 + e] = f2b(src[(size_t)j*K + k]);
  }
}

__global__ void k_pack_pg(const float* __restrict__ Wp, const float* __restrict__ Wg,
                          unsigned short* __restrict__ dst){
  int nt = blockIdx.x; // 0..8
  for(int i=threadIdx.x; i<32*64*8; i+=256){
    int kt = i>>9; int l = (i>>3)&63; int e = i&7;
    int n = nt*16 + (l&15);
    int k = ((l>>4)<<3) + kt*32 + e;
    float v = (n<MELD)? Wp[(size_t)n*HH+k] : (n==MELD? Wg[k] : 0.f);
    dst[((size_t)(nt*32 + kt)*64 + l)*8 + e] = f2b(v);
  }
}

// ---- conv path ----

__global__ void k_pad(unsigned short* __restrict__ h1pb){
  int idx = blockIdx.x*256+threadIdx.x;
  int c = idx & 511; int b = idx >> 9;
  h1pb[((size_t)b*258)*EE + c] = 0;
  h1pb[((size_t)b*258 + 257)*EE + c] = 0;
}

__global__ void k_conv1(const int* __restrict__ x, const float* __restrict__ T1,
                        const float* __restrict__ bb1, unsigned short* __restrict__ h1pb){
  int idx = blockIdx.x*256+threadIdx.x;
  int c = idx & 511; int bt = idx >> 9; int t = bt & 255; int b = bt >> 8;
  float acc = bb1[c];
  if(t > 0)    acc += T1[(size_t)(x[b*TT+t-1]*3+0)*EE+c];
               acc += T1[(size_t)(x[b*TT+t  ]*3+1)*EE+c];
  if(t < TT-1) acc += T1[(size_t)(x[b*TT+t+1]*3+2)*EE+c];
  h1pb[((size_t)b*258 + t + 1)*EE + c] = f2b(fmaxf(acc, 0.f));
}

template<int NKT>
__device__ __forceinline__ void mm_seg_stream(const unsigned short* A, int lda,
    const unsigned short* Wrow, f32x4& acc0, f32x4& acc1, int l, int wv){
  int r0 = wv*32 + (l&15);
  int k8 = (l>>4)*8;
  const unsigned short* a0 = A + (size_t)r0*lda + k8;
  const unsigned short* a1 = a0 + 16*lda;
  const unsigned short* wp = Wrow + k8;
  #pragma unroll
  for(int kt=0;kt<NKT;kt++){
    bfv8 bv = *(const bfv8*)(const void*)(wp + kt*32);
    acc0 = mfma16(*(const bfv8*)(const void*)(a0 + kt*32), bv, acc0);
    acc1 = mfma16(*(const bfv8*)(const void*)(a1 + kt*32), bv, acc1);
  }
}

__global__ __launch_bounds__(256,2) void k_conv2mm(const unsigned short* __restrict__ h1pb,
    const unsigned short* __restrict__ Wr2b, const float* __restrict__ bb2,
    unsigned short* __restrict__ h2b){
  int b = blockIdx.x;    // 0..127
  int th = blockIdx.y;   // 0..1
  int nt = blockIdx.z;   // 0..31
  int tid=threadIdx.x; int wv=tid>>6, l=tid&63;
  const unsigned short* A = h1pb + ((size_t)b*258 + th*128)*EE;
  const unsigned short* Wrow = Wr2b + (size_t)(nt*16+(l&15))*1536;
  f32x4 acc0={0,0,0,0}, acc1={0,0,0,0};
  mm_seg_stream<48>(A, EE, Wrow, acc0, acc1, l, wv);
  int rr=(l>>4)*4, cc=l&15;
  int n = nt*16+cc;
  float bias = bb2[n];
  #pragma unroll
  for(int mi=0;mi<2;mi++){
    f32x4 acc = mi?acc1:acc0;
    int tb = th*128 + wv*32 + mi*16 + rr;
    #pragma unroll
    for(int q=0;q<4;q++){
      float v = fmaxf(acc[q]+bias, 0.f);
      h2b[((size_t)(tb+q)*BB + b)*EE + n] = f2b(v);
    }
  }
}

// ---- barrier: round-8 counting barrier. gen is ALWAYS agent-scope (proven
// progress); only the cnt RMW chain goes L2-local in fast mode. Sync can
// never deadlock regardless of transport assumptions. ----
__device__ __forceinline__ void g_arrive(unsigned int* cnt, unsigned int* gen, bool fastp){
  __syncthreads();   // drains vmcnt: h-stores are in L2 (fast) / at CP (slow)
  if(threadIdx.x == 0){
    unsigned int old;
    if(fastp){
      old = __hip_atomic_fetch_add(cnt, 1u, __ATOMIC_RELAXED, __HIP_MEMORY_SCOPE_WORKGROUP);
      if(old == 31u)
        __hip_atomic_store(cnt, 0u, __ATOMIC_RELAXED, __HIP_MEMORY_SCOPE_WORKGROUP);
    } else {
      old = __hip_atomic_fetch_add(cnt, 1u, __ATOMIC_RELAXED, __HIP_MEMORY_SCOPE_AGENT);
      if(old == 31u)
        __hip_atomic_store(cnt, 0u, __ATOMIC_RELAXED, __HIP_MEMORY_SCOPE_AGENT);
    }
    if(old == 31u)
      __hip_atomic_fetch_add(gen, 1u, __ATOMIC_RELAXED, __HIP_MEMORY_SCOPE_AGENT);
  }
}
__device__ __forceinline__ void g_wait(unsigned int* gen, unsigned int target){
  if(threadIdx.x == 0){
    while(__hip_atomic_load(gen, __ATOMIC_RELAXED, __HIP_MEMORY_SCOPE_AGENT) < target)
      __builtin_amdgcn_s_sleep(1);
  }
  asm volatile("" ::: "memory");
  __syncthreads();
}

// ---- h transport: FAST = plain store to XCD L2 + sc0 (L1-bypass) reads;
// SLOW = agent-scope (coherence point), identical to round 8. Wrong-fast
// failure mode = wrong numbers, never a hang (barrier is transport-free). ----
__device__ __forceinline__ void h_store(unsigned int* ptr, unsigned int val, bool fastp){
  if(fastp) __hip_atomic_store(ptr, val, __ATOMIC_RELAXED, __HIP_MEMORY_SCOPE_WORKGROUP);
  else      __hip_atomic_store(ptr, val, __ATOMIC_RELAXED, __HIP_MEMORY_SCOPE_AGENT);
}
__device__ __forceinline__ void h_store64(unsigned long long* ptr, unsigned long long val, bool fastp){
  if(fastp) __hip_atomic_store(ptr, val, __ATOMIC_RELAXED, __HIP_MEMORY_SCOPE_WORKGROUP);
  else      __hip_atomic_store(ptr, val, __ATOMIC_RELAXED, __HIP_MEMORY_SCOPE_AGENT);
}

__device__ __forceinline__ void stage_h(unsigned short* hs, const unsigned short* slotp,
                                        int bg, int tid, bool fastp){
  if(fastp){
    const char* base = (const char*)(slotp + (size_t)(bg*16)*HH);
    #pragma unroll
    for(int jj=0;jj<2;jj++){
      int i0 = tid + (jj*2+0)*512, i1 = tid + (jj*2+1)*512;
      int r0 = i0>>7, c0 = i0&127, r1 = i1>>7, c1 = i1&127;
      int o0 = r0*2048 + c0*16,     o1 = r1*2048 + c1*16;
      u32x4 v0, v1;
      asm volatile(
        "global_load_dwordx4 %0, %2, off sc0\n\t"
        "global_load_dwordx4 %1, %3, off sc0\n\t"
        "s_waitcnt vmcnt(0)"
        : "=&v"(v0), "=&v"(v1)
        : "v"(base + o0), "v"(base + o1)
        : "memory");
      *(u32x4*)((char*)hs + (o0 ^ ((r0&7)<<4))) = v0;
      *(u32x4*)((char*)hs + (o1 ^ ((r1&7)<<4))) = v1;
    }
  } else {
    for(int i = tid; i < 4096; i += 512){
      int r = i >> 8, c8 = i & 255;
      const unsigned long long* p =
        (const unsigned long long*)(slotp + (size_t)(bg*16+r)*HH + c8*4);
      unsigned long long v = __hip_atomic_load(p, __ATOMIC_RELAXED, __HIP_MEMORY_SCOPE_AGENT);
      *(unsigned long long*)((char*)hs + ((r*2048 + c8*8) ^ ((r&7)<<4))) = v;
    }
  }
}

// ---- persistent recurrence: 256 WGs = 8 batch-groups x 32 col-groups.
// bg = bid&7: same-XCD group under round-robin dispatch (detected, not
// assumed: if placement differs, group falls back to the round-8 path). ----
__global__ __launch_bounds__(512,1) void k_recur(
  const unsigned short* __restrict__ h2b, unsigned short* __restrict__ ring,
  const unsigned short* __restrict__ WencR, const unsigned short* __restrict__ WihS,
  const unsigned short* __restrict__ W2cR, const unsigned short* __restrict__ WhhdS,
  const unsigned short* __restrict__ WpgS,
  const float* __restrict__ bhe, const float* __restrict__ bd, const float* __restrict__ b2,
  const float* __restrict__ bp, const float* __restrict__ bgp,
  unsigned int* __restrict__ bar,
  const int* __restrict__ tlen, const int* __restrict__ mlen,
  float* __restrict__ outmel, float* __restrict__ outgate)
{
  __shared__ __align__(16) unsigned short hs[16*1024];  // 32KB
  __shared__ __align__(16) unsigned short Xs[16*512];   // 16KB
  __shared__ float Gs[16][132];
  __shared__ unsigned s_ids[32];
  __shared__ int s_fast;

  const int bid = blockIdx.x;
  const int bg = bid & 7, cg = bid >> 3;
  const int tid = threadIdx.x;
  const int wvi = tid >> 6, l = tid & 63;
  const int tile = cg*8 + wvi;
  unsigned int* cnt = bar + bg*32;
  unsigned int* gen = bar + 256 + bg*32;
  unsigned int* xtab = bar + 512;
  unsigned int ge = 1;

  // ---- placement detection (no cross-lane builtins; cannot hang: all 256
  // co-resident WGs store their id before any barrier) ----
  if(tid == 0){
    unsigned id;
    asm volatile("s_getreg_b32 %0, hwreg(HW_REG_XCC_ID)" : "=s"(id));
    __hip_atomic_store(xtab + bid, id + 1u, __ATOMIC_RELAXED, __HIP_MEMORY_SCOPE_AGENT);
  }
  if(tid < 32){
    unsigned v;
    do {
      v = __hip_atomic_load(xtab + (tid*8 + bg), __ATOMIC_RELAXED, __HIP_MEMORY_SCOPE_AGENT);
    } while(v == 0u);
    s_ids[tid] = v;
  }
  __syncthreads();
  if(tid == 0){
    int f = 1;
    for(int i=1;i<32;i++) if(s_ids[i] != s_ids[0]) f = 0;
    s_fast = f;
  }
  __syncthreads();
  const bool fastp = (s_fast != 0);

  const int fr = l & 15;
  const int hswz = (fr & 7) << 4;
  const int hbase = fr*2048 + ((l>>4)<<4);
  const int xbase = fr*1024 + ((l>>4)<<4);

  const int lr = tid >> 4;
  const int lc = (tid & 15) * 2;
  const int hcol = cg*32 + lc;
  float cs0 = 0.f, cs1 = 0.f;
  unsigned int hp = 0u;
  int mylen = 0;
  if(tid < 256) mylen = tlen[bg*16 + lr];

  // zero enc h_0 (slot 100)
  if(tid < 128){
    int r = tid >> 3, c4 = (tid & 7) * 4;
    unsigned long long* p = (unsigned long long*)
      (ring + (size_t)100*BB*HH + (size_t)(bg*16+r)*HH + cg*32 + c4);
    h_store64(p, 0ull, fastp);
  }
  g_arrive(cnt, gen, fastp);

  f32x4 bw[32];

  // ================= encoder: 256 steps =================
  {
    const f32x4* wsrc = (const f32x4*)(const void*)(WencR + ((size_t)(tile*32)*64 + l)*8);
    #pragma unroll
    for(int kt=0;kt<32;kt++) bw[kt] = wsrc[kt*64];
    #pragma unroll
    for(int kt=0;kt<32;kt++) asm volatile("" : "+v"(bw[kt]));
  }

  float ei0=0,ei1=0,ef0=0,ef1=0,eg0=0,eg1=0,eo0=0,eo1=0;
  if(tid < 256){
    ei0=bhe[hcol];      ei1=bhe[hcol+1];
    ef0=bhe[HH+hcol];   ef1=bhe[HH+hcol+1];
    eg0=bhe[2*HH+hcol]; eg1=bhe[2*HH+hcol+1];
    eo0=bhe[3*HH+hcol]; eo1=bhe[3*HH+hcol+1];
  }

  #pragma unroll 1
  for(int t=0;t<TT;t++){
    {
      const uint4* src = (const uint4*)(h2b + (size_t)(t*BB + bg*16)*EE);
      for(int i = tid; i < 1024; i += 512){
        int r = i >> 6, c16 = i & 63;
        uint4 v = src[r*64 + c16];
        *(uint4*)((char*)Xs + ((r*1024 + c16*16) ^ ((r&7)<<4))) = v;
      }
    }
    __syncthreads();
    f32x4 a0 = {0.f,0.f,0.f,0.f}, a1 = {0.f,0.f,0.f,0.f};
    {
      const unsigned short* wsrc = WihS + (size_t)tile*16*64*8;
      #pragma unroll
      for(int kt=0;kt<16;kt+=2){
        bfv8 wf0 = *(const bfv8*)(const void*)(wsrc + ((size_t)kt*64 + l)*8);
        bfv8 wf1 = *(const bfv8*)(const void*)(wsrc + ((size_t)(kt+1)*64 + l)*8);
        bfv8 xv0 = *(const bfv8*)(const void*)((const char*)Xs + ((xbase + kt*64) ^ hswz));
        bfv8 xv1 = *(const bfv8*)(const void*)((const char*)Xs + ((xbase + (kt+1)*64) ^ hswz));
        a0 = mfma16(xv0, wf0, a0);
        a1 = mfma16(xv1, wf1, a1);
      }
    }
    g_wait(gen, ge);   // h_t ready
    stage_h(hs, ring + (size_t)(100 + (t&1))*BB*HH, bg, tid, fastp);
    __syncthreads();
    #pragma unroll
    for(int kt=0;kt<32;kt+=2){
      bfv8 hv0 = *(const bfv8*)(const void*)((const char*)hs + ((hbase + kt*64) ^ hswz));
      bfv8 hv1 = *(const bfv8*)(const void*)((const char*)hs + ((hbase + (kt+1)*64) ^ hswz));
      a0 = mfma16(hv0, __builtin_bit_cast(bfv8, bw[kt]), a0);
      a1 = mfma16(hv1, __builtin_bit_cast(bfv8, bw[kt+1]), a1);
    }
    {
      f32x4 acc = a0 + a1;
      int rr = (l>>4)*4;
      #pragma unroll
      for(int q=0;q<4;q++) Gs[rr+q][wvi*16 + fr] = acc[q];
    }
    __syncthreads();
    if(tid < 256){
      float gi0 = Gs[lr][lc]    + ei0, gi1 = Gs[lr][lc+1] + ei1;
      float gf0 = Gs[lr][32+lc] + ef0, gf1 = Gs[lr][33+lc] + ef1;
      float gg0 = Gs[lr][64+lc] + eg0, gg1 = Gs[lr][65+lc] + eg1;
      float go0 = Gs[lr][96+lc] + eo0, go1 = Gs[lr][97+lc] + eo1;
      float c20 = sigm(gf0)*cs0 + sigm(gi0)*tanhf(gg0);
      float c21 = sigm(gf1)*cs1 + sigm(gi1)*tanhf(gg1);
      float h20 = sigm(go0)*tanhf(c20);
      float h21 = sigm(go1)*tanhf(c21);
      if(t < mylen){
        cs0 = c20; cs1 = c21;
        hp = (unsigned)f2b(h20) | ((unsigned)f2b(h21)<<16);
      }
      unsigned short* outslot = (t==TT-1) ? (ring + (size_t)99*BB*HH)
                                          : (ring + (size_t)(100 + ((t+1)&1))*BB*HH);
      h_store((unsigned int*)(outslot + (size_t)(bg*16+lr)*HH + hcol), hp, fastp);
    }
    g_arrive(cnt, gen, fastp); ge++;
  }

  // ================= decoder: 800 steps =================
  {
    const f32x4* wsrc = (const f32x4*)(const void*)(W2cR + ((size_t)(tile*32)*64 + l)*8);
    #pragma unroll
    for(int kt=0;kt<32;kt++) bw[kt] = wsrc[kt*64];
    #pragma unroll
    for(int kt=0;kt<32;kt++) asm volatile("" : "+v"(bw[kt]));
  }

  float di0=0,di1=0,df0=0,df1=0,dg0=0,dg1=0,do0=0,do1=0;
  if(tid < 256){
    di0=b2[hcol];      di1=b2[hcol+1];
    df0=b2[HH+hcol];   df1=b2[HH+hcol+1];
    dg0=b2[2*HH+hcol]; dg1=b2[2*HH+hcol+1];
    do0=b2[3*HH+hcol]; do1=b2[3*HH+hcol+1];
  }

  #pragma unroll 1
  for(int t=0;t<TMEL;t++){
    g_wait(gen, ge);   // s_t ready
    const unsigned short* slotin = (t==0) ? ring + (size_t)99*BB*HH
                                          : ring + (size_t)((t-1)%100)*BB*HH;
    stage_h(hs, slotin, bg, tid, fastp);
    __syncthreads();
    f32x4 a0 = {0.f,0.f,0.f,0.f}, a1 = {0.f,0.f,0.f,0.f};
    if(t == 0){
      const unsigned short* wsrc = WhhdS + (size_t)tile*32*64*8;
      #pragma unroll
      for(int kt=0;kt<32;kt+=2){
        bfv8 wf0 = *(const bfv8*)(const void*)(wsrc + ((size_t)kt*64 + l)*8);
        bfv8 wf1 = *(const bfv8*)(const void*)(wsrc + ((size_t)(kt+1)*64 + l)*8);
        bfv8 hv0 = *(const bfv8*)(const void*)((const char*)hs + ((hbase + kt*64) ^ hswz));
        bfv8 hv1 = *(const bfv8*)(const void*)((const char*)hs + ((hbase + (kt+1)*64) ^ hswz));
        a0 = mfma16(hv0, wf0, a0);
        a1 = mfma16(hv1, wf1, a1);
      }
    } else {
      #pragma unroll
      for(int kt=0;kt<32;kt+=2){
        bfv8 hv0 = *(const bfv8*)(const void*)((const char*)hs + ((hbase + kt*64) ^ hswz));
        bfv8 hv1 = *(const bfv8*)(const void*)((const char*)hs + ((hbase + (kt+1)*64) ^ hswz));
        a0 = mfma16(hv0, __builtin_bit_cast(bfv8, bw[kt]), a0);
        a1 = mfma16(hv1, __builtin_bit_cast(bfv8, bw[kt+1]), a1);
      }
    }
    {
      f32x4 acc = a0 + a1;
      int rr = (l>>4)*4;
      #pragma unroll
      for(int q=0;q<4;q++) Gs[rr+q][wvi*16 + fr] = acc[q];
    }
    __syncthreads();
    if(tid < 256){
      float bi0=di0,bi1=di1,bf0=df0,bf1=df1,bg0=dg0,bg1=dg1,bo0=do0,bo1=do1;
      if(t==0){
        bi0=bd[hcol];      bi1=bd[hcol+1];
        bf0=bd[HH+hcol];   bf1=bd[HH+hcol+1];
        bg0=bd[2*HH+hcol]; bg1=bd[2*HH+hcol+1];
        bo0=bd[3*HH+hcol]; bo1=bd[3*HH+hcol+1];
      }
      float gi0 = Gs[lr][lc]    + bi0, gi1 = Gs[lr][lc+1] + bi1;
      float gf0 = Gs[lr][32+lc] + bf0, gf1 = Gs[lr][33+lc] + bf1;
      float gg0 = Gs[lr][64+lc] + bg0, gg1 = Gs[lr][65+lc] + bg1;
      float go0 = Gs[lr][96+lc] + bo0, go1 = Gs[lr][97+lc] + bo1;
      float c20 = sigm(gf0)*cs0 + sigm(gi0)*tanhf(gg0);
      float c21 = sigm(gf1)*cs1 + sigm(gi1)*tanhf(gg1);
      cs0 = c20; cs1 = c21;
      float h20 = sigm(go0)*tanhf(c20);
      float h21 = sigm(go1)*tanhf(c21);
      unsigned int hn = (unsigned)f2b(h20) | ((unsigned)f2b(h21)<<16);
      unsigned short* outslot = ring + (size_t)(t%100)*BB*HH;
      h_store((unsigned int*)(outslot + (size_t)(bg*16+lr)*HH + hcol), hn, fastp);
    }
    g_arrive(cnt, gen, fastp); ge++;

    if((t%100)==99){
      g_wait(gen, ge);   // all 100 slots final
      int tbase = t - 99;
      #pragma unroll 1
      for(int s = cg; s < 100; s += 32){
        stage_h(hs, ring + (size_t)s*BB*HH, bg, tid, fastp);
        __syncthreads();
        int tout = tbase + s;
        #pragma unroll 1
        for(int pass=0; pass<2; pass++){
          int nt = (pass==0) ? wvi : 8;
          if(pass==1 && wvi!=0) break;
          const unsigned short* wsrc = WpgS + (size_t)nt*32*64*8;
          f32x4 acc = {0.f,0.f,0.f,0.f};
          #pragma unroll
          for(int kt=0;kt<32;kt++){
            bfv8 wf = *(const bfv8*)(const void*)(wsrc + ((size_t)kt*64 + l)*8);
            bfv8 hv = *(const bfv8*)(const void*)((const char*)hs + ((hbase + kt*64) ^ hswz));
            acc = mfma16(hv, wf, acc);
          }
          int n = nt*16 + fr;
          #pragma unroll
          for(int q=0;q<4;q++){
            int b = bg*16 + (l>>4)*4 + q;
            bool msk = tout > mlen[b];
            if(n < MELD)
              outmel[((size_t)b*TMEL + tout)*MELD + n] = msk ? 0.f : acc[q]+bp[n];
            else if(n == MELD)
              outgate[(size_t)b*TMEL + tout] = msk ? 1000.f : acc[q]+bgp[0];
          }
        }
        __syncthreads();
      }
      g_arrive(cnt, gen, fastp); ge++;
    }
  }
}

__global__ void k_mask(const int* __restrict__ mlen, float* __restrict__ om){
  int idx=blockIdx.x*256+threadIdx.x; if(idx>=BB*TMEL) return;
  int b=idx/TMEL, t=idx%TMEL;
  om[idx] = (t > mlen[b]) ? 1.f : 0.f;
}

extern "C" void kernel_launch(void* const* d_in, const int* in_sizes, int n_in,
                              void* d_out, int out_size, void* d_ws, size_t ws_size,
                              hipStream_t stream){
  (void)in_sizes; (void)n_in; (void)out_size; (void)ws_size;
  const int*   x    = (const int*)d_in[0];
  const int*   tlen = (const int*)d_in[1];
  const int*   mlen = (const int*)d_in[3];
  const float* emb  = (const float*)d_in[4];
  const float* elW  = (const float*)d_in[5];
  const float* elb  = (const float*)d_in[6];
  const float* c1W  = (const float*)d_in[7];
  const float* c1b  = (const float*)d_in[8];
  const float* g1   = (const float*)d_in[9];
  const float* be1  = (const float*)d_in[10];
  const float* c2W  = (const float*)d_in[11];
  const float* c2b  = (const float*)d_in[12];
  const float* g2   = (const float*)d_in[13];
  const float* be2  = (const float*)d_in[14];
  const float* Wihe = (const float*)d_in[15];
  const float* Whhe = (const float*)d_in[16];
  const float* bhe  = (const float*)d_in[17];
  const float* Wihd = (const float*)d_in[18];
  const float* Whhd = (const float*)d_in[19];
  const float* bhd  = (const float*)d_in[20];
  const float* Wp   = (const float*)d_in[21];
  const float* bp   = (const float*)d_in[22];
  const float* Wg   = (const float*)d_in[23];
  const float* bg   = (const float*)d_in[24];

  float* ws = (float*)d_ws;
  float* proj = ws + OFF_PROJ;
  float* T1   = ws + OFF_T1;
  unsigned short* Wr2b = (unsigned short*)(ws + OFF_WR2);
  float* bb1 = ws + OFF_BB1;
  float* bb2 = ws + OFF_BB2;
  float* b2  = ws + OFF_B2;
  float* W2c = ws + OFF_W2C;
  unsigned int* bar = (unsigned int*)(ws + OFF_BAR);
  unsigned short* WencR = (unsigned short*)(ws + OFF_WENCR);
  unsigned short* WihS  = (unsigned short*)(ws + OFF_WIHS);
  unsigned short* W2cR  = (unsigned short*)(ws + OFF_W2CR);
  unsigned short* WhhdS = (unsigned short*)(ws + OFF_WHHDS);
  unsigned short* WpgS  = (unsigned short*)(ws + OFF_WPGS);
  unsigned short* h2b   = (unsigned short*)(ws + OFF_H2B);
  unsigned short* h1pb  = (unsigned short*)(ws + OFF_RING); // conv scratch
  unsigned short* ring  = (unsigned short*)(ws + OFF_RING); // alias after conv2

  float* outmel  = (float*)d_out;
  float* outgate = outmel + (size_t)BB*TMEL*MELD;
  float* outmask = outgate + (size_t)BB*TMEL;

  hipMemsetAsync(bar, 0, 4096, stream);   // cnt/gen (512 u32) + xtab (256 u32)

  k_proj<<<VV,256,0,stream>>>(emb, elW, elb, proj);
  k_t1<<<dim3(VV,3),256,0,stream>>>(proj, c1W, g1, T1);
  k_wr2<<<(EE*3*EE+255)/256,256,0,stream>>>(c2W, g2, Wr2b);
  k_bb<<<2,256,0,stream>>>(c1b,g1,be1,c2b,g2,be2,bb1,bb2);
  k_b2<<<16,256,0,stream>>>(bhd, Wihd, bp, b2);
  k_w2c<<<dim3(4096/8,HH/256),256,0,stream>>>(Whhd, Wihd, Wp, W2c);
  k_pack<<<256,256,0,stream>>>(Whhe, WencR, 32, 1024);
  k_pack<<<256,256,0,stream>>>(Wihe, WihS, 16, 512);
  k_pack<<<256,256,0,stream>>>(W2c,  W2cR, 32, 1024);
  k_pack<<<256,256,0,stream>>>(Whhd, WhhdS, 32, 1024);
  k_pack_pg<<<9,256,0,stream>>>(Wp, Wg, WpgS);
  k_pad<<<256,256,0,stream>>>(h1pb);
  k_conv1<<<65536,256,0,stream>>>(x, T1, bb1, h1pb);
  k_conv2mm<<<dim3(BB,2,32),256,0,stream>>>(h1pb, Wr2b, bb2, h2b);

  void* kargs[] = {
    (void*)&h2b, (void*)&ring, (void*)&WencR, (void*)&WihS, (void*)&W2cR, (void*)&WhhdS,
    (void*)&WpgS, (void*)&bhe, (void*)&bhd, (void*)&b2, (void*)&bp, (void*)&bg,
    (void*)&bar, (void*)&tlen, (void*)&mlen, (void*)&outmel, (void*)&outgate
  };
  hipLaunchCooperativeKernel((void*)k_recur, dim3(256), dim3(512), kargs, 0u, stream);

  k_mask<<<(BB*TMEL+255)/256,256,0,stream>>>(mlen, outmask);
}